// Round 1
// 2640.011 us; speedup vs baseline: 1.0250x; 1.0250x over previous
//
#include <hip/hip_runtime.h>

#define S_LEN 2048
#define DIM   4096
#define NH    32
#define HD    128
#define FF    11008

#define BM 128
#define BN 128
#define BK 32

typedef __attribute__((ext_vector_type(8))) short bf16x8;   // 8 bf16 = 4 VGPRs (guide §3)
typedef __attribute__((ext_vector_type(4))) float f32x4;

enum { GF_OUTF32 = 1, GF_CSKIP = 2, GF_CKLIM = 4, GF_RES = 8 };

__device__ __forceinline__ unsigned short f2b(float f) {
  union { float f; unsigned int u; } v; v.f = f;
  return (unsigned short)((v.u + 0x7FFFu + ((v.u >> 16) & 1u)) >> 16);  // RNE
}
__device__ __forceinline__ float b2f(unsigned short b) {
  union { unsigned int u; float f; } v; v.u = ((unsigned int)b) << 16;
  return v.f;
}

// async 16B global -> LDS (m97 lever: width=16 emits global_load_lds_dwordx4).
// LDS dest must be wave-uniform; HW writes lane i at base + i*16 (m104/m108).
__device__ __forceinline__ void gload16(const unsigned short* g, unsigned short* l) {
  __builtin_amdgcn_global_load_lds(
      (const __attribute__((address_space(1))) void*)g,
      (__attribute__((address_space(3))) void*)l,
      16, 0, 0);
}

// ---------------------------------------------------------------------------
// GEMM: C[M,N] = scale * A[M,K] * B[N,K]^T (+ optional fp32 residual R)
// A, Bt bf16 (ushort bits). C bf16 or fp32. Batched via blockIdx.z strides.
// m97 structure: 128x128 tile, BK=32, 4 waves, global_load_lds staging.
// ---------------------------------------------------------------------------
__global__ __launch_bounds__(256) void gemm_bt(
    const unsigned short* __restrict__ A, int lda, long bsA,
    const unsigned short* __restrict__ Bt, int ldb, long bsB,
    void* __restrict__ Cv, int ldc, long bsC,
    const float* __restrict__ R,
    int M, int N, int K, float scale, int flags)
{
  const int m0 = blockIdx.y * BM;
  const int n0 = blockIdx.x * BN;
  if ((flags & GF_CSKIP) && n0 > m0 + (BM - 1)) return;  // fully-masked causal tile
  const int bz = blockIdx.z;
  A  += (long)bz * bsA;
  Bt += (long)bz * bsB;
  int Keff = K;
  if (flags & GF_CKLIM) { int kl = m0 + BM; Keff = kl < K ? kl : K; }

  __shared__ unsigned short As[BM * BK];  // [m][k] flat; LDS byte off = chunk*16 (linear)
  __shared__ unsigned short Bs[BN * BK];

  const int tid  = threadIdx.x;
  const int wave = tid >> 6;
  const int lane = tid & 63;
  const int qd   = lane >> 4;   // quad 0..3
  const int r16  = lane & 15;
  const int wm   = (wave & 1) * 64;   // 2x2 waves, each 64x64
  const int wn   = (wave >> 1) * 64;

  // per-lane source coordinates for the two 16B staging chunks
  const int c0 = tid;            // chunk 0: rows 0..63
  const int mA0 = c0 >> 2, kA0 = (c0 & 3) * 8;
  const int c1 = tid + 256;      // chunk 1: rows 64..127
  const int mA1 = c1 >> 2, kA1 = (c1 & 3) * 8;
  // wave-uniform LDS bases (elements): chunk0 at wave*512, chunk1 at 2048 + wave*512
  unsigned short* AsL0 = &As[wave * 512];
  unsigned short* AsL1 = &As[2048 + wave * 512];
  unsigned short* BsL0 = &Bs[wave * 512];
  unsigned short* BsL1 = &Bs[2048 + wave * 512];
  const unsigned short* Abase0 = A  + (long)(m0 + mA0) * lda + kA0;
  const unsigned short* Abase1 = A  + (long)(m0 + mA1) * lda + kA1;
  const unsigned short* Bbase0 = Bt + (long)(n0 + mA0) * ldb + kA0;
  const unsigned short* Bbase1 = Bt + (long)(n0 + mA1) * ldb + kA1;

  f32x4 acc[4][4];
#pragma unroll
  for (int i = 0; i < 4; i++)
#pragma unroll
    for (int j = 0; j < 4; j++)
      acc[i][j] = (f32x4){0.0f, 0.0f, 0.0f, 0.0f};

  for (int k0 = 0; k0 < Keff; k0 += BK) {
    // stage 128x32 bf16 tiles async: 4x global_load_lds_dwordx4 per thread,
    // no VGPR round-trip, no ds_write. Compiler drains vmcnt at the barrier.
    gload16(Abase0 + k0, AsL0);
    gload16(Abase1 + k0, AsL1);
    gload16(Bbase0 + k0, BsL0);
    gload16(Bbase1 + k0, BsL1);
    __syncthreads();
    bf16x8 af[4], bfr[4];
#pragma unroll
    for (int i = 0; i < 4; i++)
      af[i] = *(const bf16x8*)(&As[(wm + i * 16 + r16) * BK + qd * 8]);
#pragma unroll
    for (int j = 0; j < 4; j++)
      bfr[j] = *(const bf16x8*)(&Bs[(wn + j * 16 + r16) * BK + qd * 8]);
#pragma unroll
    for (int i = 0; i < 4; i++)
#pragma unroll
      for (int j = 0; j < 4; j++)
        acc[i][j] = __builtin_amdgcn_mfma_f32_16x16x32_bf16(af[i], bfr[j], acc[i][j], 0, 0, 0);
    __syncthreads();
  }

  // epilogue: C[row=wm+i*16+qd*4+t][col=wn+j*16+r16] = acc[i][j][t]  (verified C/D map)
  float* Cf = (float*)Cv + (long)bz * bsC;
  unsigned short* Ch = (unsigned short*)Cv + (long)bz * bsC;
#pragma unroll
  for (int i = 0; i < 4; i++) {
    const int row = m0 + wm + i * 16 + qd * 4;
#pragma unroll
    for (int j = 0; j < 4; j++) {
      const int col = n0 + wn + j * 16 + r16;
#pragma unroll
      for (int t = 0; t < 4; t++) {
        long idx = (long)(row + t) * ldc + col;
        float v = acc[i][j][t] * scale;
        if (flags & GF_RES) v += R[idx];
        if (flags & GF_OUTF32) Cf[idx] = v;
        else Ch[idx] = f2b(v);
      }
    }
  }
}

// ---------------------------------------------------------------------------
// RMSNorm: per-row, fp32 in -> bf16 out
// ---------------------------------------------------------------------------
__global__ __launch_bounds__(256) void rmsnorm_kernel(const float* __restrict__ x,
                                                      const float* __restrict__ w,
                                                      unsigned short* __restrict__ out)
{
  const long row = blockIdx.x;
  const float* xr = x + row * DIM;
  float vals[16];
  float ss = 0.0f;
#pragma unroll
  for (int t = 0; t < 16; t++) {
    float v = xr[threadIdx.x + t * 256];
    vals[t] = v; ss += v * v;
  }
#pragma unroll
  for (int o = 32; o > 0; o >>= 1) ss += __shfl_down(ss, o, 64);
  __shared__ float red[4];
  const int wv = threadIdx.x >> 6, ln = threadIdx.x & 63;
  if (ln == 0) red[wv] = ss;
  __syncthreads();
  ss = red[0] + red[1] + red[2] + red[3];
  const float scale = 1.0f / sqrtf(ss * (1.0f / (float)DIM) + 1e-6f);
#pragma unroll
  for (int t = 0; t < 16; t++) {
    int c = threadIdx.x + t * 256;
    out[row * DIM + c] = f2b(vals[t] * scale * w[c]);
  }
}

// ---------------------------------------------------------------------------
// RoPE in-place on bf16 (S,H,HD); cos/sin fp32 (S, HD/2)
// ---------------------------------------------------------------------------
__global__ __launch_bounds__(256) void rope_kernel(unsigned short* __restrict__ xq,
                                                   const float* __restrict__ cosb,
                                                   const float* __restrict__ sinb)
{
  const int idx = blockIdx.x * 256 + threadIdx.x;   // pair index
  if (idx >= S_LEN * NH * 64) return;
  const int i = idx & 63;
  const int h = (idx >> 6) & (NH - 1);
  const int s = idx >> 11;
  const long base = (long)s * DIM + h * HD + 2 * i;
  const float xr = b2f(xq[base]), xi = b2f(xq[base + 1]);
  const float c = cosb[s * 64 + i], sn = sinb[s * 64 + i];
  xq[base]     = f2b(xr * c - xi * sn);
  xq[base + 1] = f2b(xr * sn + xi * c);
}

// ---------------------------------------------------------------------------
// Causal softmax in-place on one bf16 score row; zeros above diagonal
// ---------------------------------------------------------------------------
__global__ __launch_bounds__(256) void softmax_kernel(unsigned short* __restrict__ sc)
{
  const int s  = blockIdx.x;
  const int hz = blockIdx.y;
  unsigned short* row = sc + ((long)hz * S_LEN + s) * S_LEN;
  __shared__ float buf[S_LEN];
  __shared__ float redA[4], redB[4];
  const int tid = threadIdx.x;
  const int wv = tid >> 6, ln = tid & 63;
  const int valid = s + 1;

  float mx = -3.0e38f;
  for (int c = tid; c < valid; c += 256) { float v = b2f(row[c]); buf[c] = v; mx = fmaxf(mx, v); }
#pragma unroll
  for (int o = 32; o > 0; o >>= 1) mx = fmaxf(mx, __shfl_down(mx, o, 64));
  if (ln == 0) redA[wv] = mx;
  __syncthreads();
  mx = fmaxf(fmaxf(redA[0], redA[1]), fmaxf(redA[2], redA[3]));

  float sum = 0.0f;
  for (int c = tid; c < valid; c += 256) { float e = __expf(buf[c] - mx); buf[c] = e; sum += e; }
#pragma unroll
  for (int o = 32; o > 0; o >>= 1) sum += __shfl_down(sum, o, 64);
  if (ln == 0) redB[wv] = sum;
  __syncthreads();
  sum = redB[0] + redB[1] + redB[2] + redB[3];
  const float inv = 1.0f / sum;
  for (int c = tid; c < S_LEN; c += 256)
    row[c] = (c < valid) ? f2b(buf[c] * inv) : (unsigned short)0;
}

// ---------------------------------------------------------------------------
// ffin = silu(a1) * a3  (bf16)
// ---------------------------------------------------------------------------
__global__ __launch_bounds__(256) void silu_mul_kernel(const unsigned short* __restrict__ a1,
                                                       const unsigned short* __restrict__ a3,
                                                       unsigned short* __restrict__ o, long n)
{
  const long i = (long)blockIdx.x * 256 + threadIdx.x;
  if (i >= n) return;
  const float xv = b2f(a1[i]);
  const float g = xv / (1.0f + __expf(-xv));
  o[i] = f2b(g * b2f(a3[i]));
}

// ---------------------------------------------------------------------------
// Transpose + cast fp32 (rows x cols) -> bf16 (cols x rows)
// ---------------------------------------------------------------------------
__global__ __launch_bounds__(256) void transpose_cast_kernel(const float* __restrict__ in,
                                                             unsigned short* __restrict__ out,
                                                             int rows, int cols)
{
  __shared__ unsigned short tile[32][33];
  const int c0 = blockIdx.x * 32, r0 = blockIdx.y * 32;
  const int tx = threadIdx.x & 31, ty = threadIdx.x >> 5;  // ty 0..7
#pragma unroll
  for (int i = 0; i < 4; i++) {
    int rr = ty + i * 8;
    tile[rr][tx] = f2b(in[(long)(r0 + rr) * cols + (c0 + tx)]);
  }
  __syncthreads();
#pragma unroll
  for (int i = 0; i < 4; i++) {
    int rr = ty + i * 8;
    out[(long)(c0 + rr) * rows + (r0 + tx)] = tile[tx][rr];
  }
}

// ---------------------------------------------------------------------------
// Batched bf16 transpose: per batch, in (rows x cols, ld_in) -> out (cols x rows, ld_out)
// ---------------------------------------------------------------------------
__global__ __launch_bounds__(256) void transpose_bf16_kernel(const unsigned short* __restrict__ in,
                                                             long in_bs, int ld_in,
                                                             unsigned short* __restrict__ out,
                                                             long out_bs, int ld_out,
                                                             int rows, int cols)
{
  const int b = blockIdx.z;
  in  += (long)b * in_bs;
  out += (long)b * out_bs;
  __shared__ unsigned short tile[32][33];
  const int c0 = blockIdx.x * 32, r0 = blockIdx.y * 32;
  const int tx = threadIdx.x & 31, ty = threadIdx.x >> 5;
#pragma unroll
  for (int i = 0; i < 4; i++)
    tile[ty + i * 8][tx] = in[(long)(r0 + ty + i * 8) * ld_in + (c0 + tx)];
  __syncthreads();
#pragma unroll
  for (int i = 0; i < 4; i++)
    out[(long)(c0 + ty + i * 8) * ld_out + (r0 + tx)] = tile[tx][ty + i * 8];
}

// ---------------------------------------------------------------------------
extern "C" void kernel_launch(void* const* d_in, const int* in_sizes, int n_in,
                              void* d_out, int out_size, void* d_ws, size_t ws_size,
                              hipStream_t stream)
{
  const float* x    = (const float*)d_in[0];
  const float* wq   = (const float*)d_in[1];
  const float* wk   = (const float*)d_in[2];
  const float* wv   = (const float*)d_in[3];
  const float* wo   = (const float*)d_in[4];
  const float* w1   = (const float*)d_in[5];
  const float* w2   = (const float*)d_in[6];   // NOTE: w2 before w3 in dict order
  const float* w3   = (const float*)d_in[7];
  const float* anw  = (const float*)d_in[8];
  const float* fnw  = (const float*)d_in[9];
  const float* cosb = (const float*)d_in[10];
  const float* sinb = (const float*)d_in[11];
  float* out = (float*)d_out;

  // workspace layout (~310 MB, phase-overlaid)
  char* ws = (char*)d_ws;
  size_t o = 0;
  unsigned short* wT   = (unsigned short*)(ws + o); o += 90177536ULL;   // rotating W^T (max FFxD bf16)
  unsigned short* hn   = (unsigned short*)(ws + o); o += 16777216ULL;   // rmsnorm1 out, bf16
  unsigned short* attnb= (unsigned short*)(ws + o); o += 16777216ULL;   // attention out, bf16
  float*          hbuf = (float*)(ws + o);          o += 33554432ULL;   // h = x + attn@wo, fp32
  unsigned short* fn   = (unsigned short*)(ws + o); o += 16777216ULL;   // rmsnorm2 out, bf16
  char* ovl = ws + o;                                                   // overlay region (135.3 MB)
  // attention phase
  unsigned short* qb = (unsigned short*)(ovl);
  unsigned short* kb = (unsigned short*)(ovl + 16777216ULL);
  unsigned short* vb = (unsigned short*)(ovl + 2 * 16777216ULL);
  unsigned short* vT = (unsigned short*)(ovl + 3 * 16777216ULL);
  unsigned short* sc = (unsigned short*)(ovl + 4 * 16777216ULL);        // 8 heads of SxS bf16
  // ffn phase (reuses the same region after attention is consumed)
  unsigned short* a1   = (unsigned short*)(ovl);
  unsigned short* a3   = (unsigned short*)(ovl + 45088768ULL);
  unsigned short* ffin = (unsigned short*)(ovl + 2 * 45088768ULL);

  const dim3 blk(256);
  const dim3 tgD(DIM / 32, DIM / 32);
  const dim3 gqkv(DIM / BN, S_LEN / BM, 1);

  // 1. hn = rmsnorm(x, attn_norm_w)
  rmsnorm_kernel<<<S_LEN, blk, 0, stream>>>(x, anw, hn);

  // 2. q,k,v = hn @ {wq,wk,wv}  (transpose each weight into rotating buffer first)
  transpose_cast_kernel<<<tgD, blk, 0, stream>>>(wq, wT, DIM, DIM);
  gemm_bt<<<gqkv, blk, 0, stream>>>(hn, DIM, 0, wT, DIM, 0, qb, DIM, 0, nullptr,
                                    S_LEN, DIM, DIM, 1.0f, 0);
  transpose_cast_kernel<<<tgD, blk, 0, stream>>>(wk, wT, DIM, DIM);
  gemm_bt<<<gqkv, blk, 0, stream>>>(hn, DIM, 0, wT, DIM, 0, kb, DIM, 0, nullptr,
                                    S_LEN, DIM, DIM, 1.0f, 0);
  transpose_cast_kernel<<<tgD, blk, 0, stream>>>(wv, wT, DIM, DIM);
  gemm_bt<<<gqkv, blk, 0, stream>>>(hn, DIM, 0, wT, DIM, 0, vb, DIM, 0, nullptr,
                                    S_LEN, DIM, DIM, 1.0f, 0);

  // 3. RoPE on q, k (in place)
  rope_kernel<<<(S_LEN * NH * 64) / 256, blk, 0, stream>>>(qb, cosb, sinb);
  rope_kernel<<<(S_LEN * NH * 64) / 256, blk, 0, stream>>>(kb, cosb, sinb);

  // 4. vT[h][d][s] = v[s][h][d]
  const dim3 tv(HD / 32, S_LEN / 32, NH);
  transpose_bf16_kernel<<<tv, blk, 0, stream>>>(vb, (long)HD, DIM,
                                                vT, (long)HD * S_LEN, S_LEN, S_LEN, HD);

  // 5. attention, 4 chunks of 8 heads (score buffer reused)
  const float sscale = 0.08838834764831845f;  // 1/sqrt(128)
  for (int ch = 0; ch < 4; ch++) {
    const int h0 = ch * 8;
    const dim3 gs(S_LEN / BN, S_LEN / BM, 8);
    gemm_bt<<<gs, blk, 0, stream>>>(qb + h0 * HD, DIM, (long)HD,
                                    kb + h0 * HD, DIM, (long)HD,
                                    sc, S_LEN, (long)S_LEN * S_LEN, nullptr,
                                    S_LEN, S_LEN, HD, sscale, GF_CSKIP);
    const dim3 gsm(S_LEN, 8);
    softmax_kernel<<<gsm, blk, 0, stream>>>(sc);
    const dim3 gpv(HD / BN, S_LEN / BM, 8);
    gemm_bt<<<gpv, blk, 0, stream>>>(sc, S_LEN, (long)S_LEN * S_LEN,
                                     vT + (long)h0 * HD * S_LEN, S_LEN, (long)HD * S_LEN,
                                     attnb + h0 * HD, DIM, (long)HD, nullptr,
                                     S_LEN, HD, S_LEN, 1.0f, GF_CKLIM);
  }

  // 6. h = x + attn @ wo
  transpose_cast_kernel<<<tgD, blk, 0, stream>>>(wo, wT, DIM, DIM);
  gemm_bt<<<gqkv, blk, 0, stream>>>(attnb, DIM, 0, wT, DIM, 0, hbuf, DIM, 0, x,
                                    S_LEN, DIM, DIM, 1.0f, GF_OUTF32 | GF_RES);

  // 7. fn = rmsnorm(h, ffn_norm_w)
  rmsnorm_kernel<<<S_LEN, blk, 0, stream>>>(hbuf, fnw, fn);

  // 8. a1 = fn@w1 ; a3 = fn@w3
  const dim3 tg1(FF / 32, DIM / 32);
  const dim3 gff(FF / BN, S_LEN / BM, 1);
  transpose_cast_kernel<<<tg1, blk, 0, stream>>>(w1, wT, DIM, FF);
  gemm_bt<<<gff, blk, 0, stream>>>(fn, DIM, 0, wT, DIM, 0, a1, FF, 0, nullptr,
                                   S_LEN, FF, DIM, 1.0f, 0);
  transpose_cast_kernel<<<tg1, blk, 0, stream>>>(w3, wT, DIM, FF);
  gemm_bt<<<gff, blk, 0, stream>>>(fn, DIM, 0, wT, DIM, 0, a3, FF, 0, nullptr,
                                   S_LEN, FF, DIM, 1.0f, 0);

  // 9. ffin = silu(a1) * a3
  silu_mul_kernel<<<(S_LEN * FF) / 256, blk, 0, stream>>>(a1, a3, ffin, (long)S_LEN * FF);

  // 10. out = h + ffin @ w2
  const dim3 tg2(DIM / 32, FF / 32);
  const dim3 gout(DIM / BN, S_LEN / BM, 1);
  transpose_cast_kernel<<<tg2, blk, 0, stream>>>(w2, wT, FF, DIM);
  gemm_bt<<<gout, blk, 0, stream>>>(ffin, FF, 0, wT, FF, 0, out, DIM, 0, hbuf,
                                    S_LEN, DIM, FF, 1.0f, GF_OUTF32 | GF_RES);
}

// Round 2
// 2478.153 us; speedup vs baseline: 1.0919x; 1.0653x over previous
//
#include <hip/hip_runtime.h>

#define S_LEN 2048
#define DIM   4096
#define NH    32
#define HD    128
#define FF    11008

#define BM 128
#define BN 128
#define BK 32

#define QBM 256
#define QBN 256
#define QBK 64

typedef __attribute__((ext_vector_type(8))) short bf16x8;   // 8 bf16 = 4 VGPRs
typedef __attribute__((ext_vector_type(4))) float f32x4;

enum { GF_OUTF32 = 1, GF_CSKIP = 2, GF_CKLIM = 4, GF_RES = 8 };

__device__ __forceinline__ unsigned short f2b(float f) {
  union { float f; unsigned int u; } v; v.f = f;
  return (unsigned short)((v.u + 0x7FFFu + ((v.u >> 16) & 1u)) >> 16);  // RNE
}
__device__ __forceinline__ float b2f(unsigned short b) {
  union { unsigned int u; float f; } v; v.u = ((unsigned int)b) << 16;
  return v.f;
}

// async 16B global -> LDS. LDS dest wave-uniform; HW writes lane i at base+i*16.
__device__ __forceinline__ void gload16(const unsigned short* g, unsigned short* l) {
  __builtin_amdgcn_global_load_lds(
      (const __attribute__((address_space(1))) void*)g,
      (__attribute__((address_space(3))) void*)l,
      16, 0, 0);
}

// ---------------------------------------------------------------------------
// gemm256: 256x256x64 8-phase pipelined GEMM (T2+T3+T4+T5, m201 template).
// C[M,N] = scale*A[M,K]*Bt[N,K]^T (+fp32 residual). Requires M%256==0,
// N%256==0, K%64==0, K>=128. 512 threads, 128KB LDS, counted vmcnt(6).
// ---------------------------------------------------------------------------
__global__ __launch_bounds__(512, 2) void gemm256(
    const unsigned short* __restrict__ A, int lda,
    const unsigned short* __restrict__ Bt, int ldb,
    void* __restrict__ Cv, int ldc,
    const float* __restrict__ R,
    int M, int N, int K, float scale, int flags)
{
  __shared__ unsigned short lds[65536];  // [2 buf][A 16384 | B 16384] elems = 128 KiB

  // bijective XCD swizzle (m204): contiguous N-major chunks per XCD
  const int nx = gridDim.x;
  const int nwg = nx * gridDim.y;
  const int orig = blockIdx.y * nx + blockIdx.x;
  const int xcd = orig & 7, loc = orig >> 3;
  const int q8 = nwg >> 3, r8 = nwg & 7;
  const int swz = (xcd < r8 ? xcd * (q8 + 1) : r8 * (q8 + 1) + (xcd - r8) * q8) + loc;
  const int m0 = (swz / nx) * QBM;
  const int n0 = (swz % nx) * QBN;

  const int tid  = threadIdx.x;
  const int wave = tid >> 6;
  const int lane = tid & 63;
  const int qd   = lane >> 4;
  const int r16  = lane & 15;
  const int wm   = (wave >> 2) * 128;  // waves 0-3: rows 0-127; 4-7: 128-255
  const int wn   = (wave & 3) * 64;    // 4 col-strips of 64

  const int nt = K / QBK;

  // per-lane staging coords: chunk c covers (row=c>>3, slot=c&7); slot swizzled
  // on the GLOBAL side so LDS stays linear (gload_lds writes base+lane*16).
  const int srow = tid >> 3;          // 0..63 (chunk set 0); +64 for set 1
  const int sslot = tid & 7;

  // stage one 128x64 half-tile: gRow0 = global ptr at (row 0, k0) of the half
  auto stage_half = [&](const unsigned short* gRow0, int ld, int ldsBase) {
    {
      const int r = srow;
      gload16(gRow0 + (long)r * ld + ((sslot ^ (r & 7)) << 3),
              &lds[ldsBase + wave * 512]);
    }
    {
      const int r = srow + 64;
      gload16(gRow0 + (long)r * ld + ((sslot ^ (r & 7)) << 3),
              &lds[ldsBase + 4096 + wave * 512]);
    }
  };
  // region: 0=A rows 0-127, 1=A rows 128-255, 2=B rows 0-127, 3=B rows 128-255
  auto stage = [&](int tau, int region) {
    const int tc = tau < nt ? tau : nt - 1;   // clamp source only; dest keeps parity
    const int kk = tc * QBK;
    const int bb = (tau & 1) * 32768;
    switch (region) {
      case 0: stage_half(A  + (long)m0         * lda + kk, lda, bb);         break;
      case 1: stage_half(A  + (long)(m0 + 128) * lda + kk, lda, bb + 8192);  break;
      case 2: stage_half(Bt + (long)n0         * ldb + kk, ldb, bb + 16384); break;
      case 3: stage_half(Bt + (long)(n0 + 128) * ldb + kk, ldb, bb + 24576); break;
    }
  };

  // prologue: tile0 fully + tile1 {A0,A1,B0}; 3 half-tiles (6 loads) in flight
  stage(0, 0); stage(0, 1); stage(0, 2); stage(0, 3);
  stage(1, 0); stage(1, 1); stage(1, 2);
  asm volatile("s_waitcnt vmcnt(6)" ::: "memory");
  asm volatile("s_barrier" ::: "memory");

  f32x4 acc[8][4];
#pragma unroll
  for (int i = 0; i < 8; i++)
#pragma unroll
    for (int j = 0; j < 4; j++)
      acc[i][j] = (f32x4){0.0f, 0.0f, 0.0f, 0.0f};

  bf16x8 af[8][2], bf[4][2];

  for (int t = 0; t < nt; ++t) {
    const int cb = (t & 1) * 32768;
    const unsigned short* As = &lds[cb];
    const unsigned short* Bs = &lds[cb + 16384];

    // ---- P1: all A frags + B cols 0-1; stage (t+1).B1 ----
#pragma unroll
    for (int i = 0; i < 8; i++) {
      const int r = wm + i * 16 + r16;
#pragma unroll
      for (int kh = 0; kh < 2; kh++)
        af[i][kh] = *(const bf16x8*)&As[r * 64 + ((((kh << 2) | qd) ^ (r & 7)) << 3)];
    }
#pragma unroll
    for (int j = 0; j < 2; j++) {
      const int r = wn + j * 16 + r16;
#pragma unroll
      for (int kh = 0; kh < 2; kh++)
        bf[j][kh] = *(const bf16x8*)&Bs[r * 64 + ((((kh << 2) | qd) ^ (r & 7)) << 3)];
    }
    stage(t + 1, 3);
    asm volatile("s_barrier" ::: "memory");
    __builtin_amdgcn_s_setprio(1);
#pragma unroll
    for (int i = 0; i < 4; i++)
#pragma unroll
      for (int j = 0; j < 2; j++)
#pragma unroll
        for (int kh = 0; kh < 2; kh++)
          acc[i][j] = __builtin_amdgcn_mfma_f32_16x16x32_bf16(af[i][kh], bf[j][kh], acc[i][j], 0, 0, 0);
    __builtin_amdgcn_s_setprio(0);
    asm volatile("s_barrier" ::: "memory");

    // ---- P2: B cols 2-3; stage (t+2).A0 ----
#pragma unroll
    for (int j = 2; j < 4; j++) {
      const int r = wn + j * 16 + r16;
#pragma unroll
      for (int kh = 0; kh < 2; kh++)
        bf[j][kh] = *(const bf16x8*)&Bs[r * 64 + ((((kh << 2) | qd) ^ (r & 7)) << 3)];
    }
    stage(t + 2, 0);
    asm volatile("s_barrier" ::: "memory");
    __builtin_amdgcn_s_setprio(1);
#pragma unroll
    for (int i = 0; i < 4; i++)
#pragma unroll
      for (int j = 2; j < 4; j++)
#pragma unroll
        for (int kh = 0; kh < 2; kh++)
          acc[i][j] = __builtin_amdgcn_mfma_f32_16x16x32_bf16(af[i][kh], bf[j][kh], acc[i][j], 0, 0, 0);
    __builtin_amdgcn_s_setprio(0);
    asm volatile("s_barrier" ::: "memory");

    // ---- P3: stage (t+2).A1 ----
    stage(t + 2, 1);
    asm volatile("s_barrier" ::: "memory");
    __builtin_amdgcn_s_setprio(1);
#pragma unroll
    for (int i = 4; i < 8; i++)
#pragma unroll
      for (int j = 2; j < 4; j++)
#pragma unroll
        for (int kh = 0; kh < 2; kh++)
          acc[i][j] = __builtin_amdgcn_mfma_f32_16x16x32_bf16(af[i][kh], bf[j][kh], acc[i][j], 0, 0, 0);
    __builtin_amdgcn_s_setprio(0);
    asm volatile("s_barrier" ::: "memory");

    // ---- P4: stage (t+2).B0; counted drain vmcnt(6) once per K-tile ----
    stage(t + 2, 2);
    asm volatile("s_barrier" ::: "memory");
    __builtin_amdgcn_s_setprio(1);
#pragma unroll
    for (int i = 4; i < 8; i++)
#pragma unroll
      for (int j = 0; j < 2; j++)
#pragma unroll
        for (int kh = 0; kh < 2; kh++)
          acc[i][j] = __builtin_amdgcn_mfma_f32_16x16x32_bf16(af[i][kh], bf[j][kh], acc[i][j], 0, 0, 0);
    __builtin_amdgcn_s_setprio(0);
    asm volatile("s_waitcnt vmcnt(6)" ::: "memory");
    asm volatile("s_barrier" ::: "memory");
  }

  // epilogue: C[row=wm+i*16+qd*4+t][col=wn+j*16+r16] (verified C/D map)
  float* Cf = (float*)Cv;
  unsigned short* Ch = (unsigned short*)Cv;
#pragma unroll
  for (int i = 0; i < 8; i++) {
    const int row = m0 + wm + i * 16 + qd * 4;
#pragma unroll
    for (int j = 0; j < 4; j++) {
      const int col = n0 + wn + j * 16 + r16;
#pragma unroll
      for (int tt = 0; tt < 4; tt++) {
        long idx = (long)(row + tt) * ldc + col;
        float v = acc[i][j][tt] * scale;
        if (flags & GF_RES) v += R[idx];
        if (flags & GF_OUTF32) Cf[idx] = v;
        else Ch[idx] = f2b(v);
      }
    }
  }
}

// ---------------------------------------------------------------------------
// GEMM (128-tile, attention shapes): C = scale*A*Bt^T (+R). Batched via z.
// ---------------------------------------------------------------------------
__global__ __launch_bounds__(256) void gemm_bt(
    const unsigned short* __restrict__ A, int lda, long bsA,
    const unsigned short* __restrict__ Bt, int ldb, long bsB,
    void* __restrict__ Cv, int ldc, long bsC,
    const float* __restrict__ R,
    int M, int N, int K, float scale, int flags)
{
  const int m0 = blockIdx.y * BM;
  const int n0 = blockIdx.x * BN;
  if ((flags & GF_CSKIP) && n0 > m0 + (BM - 1)) return;  // fully-masked causal tile
  const int bz = blockIdx.z;
  A  += (long)bz * bsA;
  Bt += (long)bz * bsB;
  int Keff = K;
  if (flags & GF_CKLIM) { int kl = m0 + BM; Keff = kl < K ? kl : K; }

  __shared__ unsigned short As[BM * BK];
  __shared__ unsigned short Bs[BN * BK];

  const int tid  = threadIdx.x;
  const int wave = tid >> 6;
  const int lane = tid & 63;
  const int qd   = lane >> 4;
  const int r16  = lane & 15;
  const int wm   = (wave & 1) * 64;
  const int wn   = (wave >> 1) * 64;

  const int c0 = tid;
  const int mA0 = c0 >> 2, kA0 = (c0 & 3) * 8;
  const int c1 = tid + 256;
  const int mA1 = c1 >> 2, kA1 = (c1 & 3) * 8;
  unsigned short* AsL0 = &As[wave * 512];
  unsigned short* AsL1 = &As[2048 + wave * 512];
  unsigned short* BsL0 = &Bs[wave * 512];
  unsigned short* BsL1 = &Bs[2048 + wave * 512];
  const unsigned short* Abase0 = A  + (long)(m0 + mA0) * lda + kA0;
  const unsigned short* Abase1 = A  + (long)(m0 + mA1) * lda + kA1;
  const unsigned short* Bbase0 = Bt + (long)(n0 + mA0) * ldb + kA0;
  const unsigned short* Bbase1 = Bt + (long)(n0 + mA1) * ldb + kA1;

  f32x4 acc[4][4];
#pragma unroll
  for (int i = 0; i < 4; i++)
#pragma unroll
    for (int j = 0; j < 4; j++)
      acc[i][j] = (f32x4){0.0f, 0.0f, 0.0f, 0.0f};

  for (int k0 = 0; k0 < Keff; k0 += BK) {
    gload16(Abase0 + k0, AsL0);
    gload16(Abase1 + k0, AsL1);
    gload16(Bbase0 + k0, BsL0);
    gload16(Bbase1 + k0, BsL1);
    __syncthreads();
    bf16x8 af[4], bfr[4];
#pragma unroll
    for (int i = 0; i < 4; i++)
      af[i] = *(const bf16x8*)(&As[(wm + i * 16 + r16) * BK + qd * 8]);
#pragma unroll
    for (int j = 0; j < 4; j++)
      bfr[j] = *(const bf16x8*)(&Bs[(wn + j * 16 + r16) * BK + qd * 8]);
#pragma unroll
    for (int i = 0; i < 4; i++)
#pragma unroll
      for (int j = 0; j < 4; j++)
        acc[i][j] = __builtin_amdgcn_mfma_f32_16x16x32_bf16(af[i], bfr[j], acc[i][j], 0, 0, 0);
    __syncthreads();
  }

  float* Cf = (float*)Cv + (long)bz * bsC;
  unsigned short* Ch = (unsigned short*)Cv + (long)bz * bsC;
#pragma unroll
  for (int i = 0; i < 4; i++) {
    const int row = m0 + wm + i * 16 + qd * 4;
#pragma unroll
    for (int j = 0; j < 4; j++) {
      const int col = n0 + wn + j * 16 + r16;
#pragma unroll
      for (int t = 0; t < 4; t++) {
        long idx = (long)(row + t) * ldc + col;
        float v = acc[i][j][t] * scale;
        if (flags & GF_RES) v += R[idx];
        if (flags & GF_OUTF32) Cf[idx] = v;
        else Ch[idx] = f2b(v);
      }
    }
  }
}

// ---------------------------------------------------------------------------
// RMSNorm: per-row, fp32 in -> bf16 out
// ---------------------------------------------------------------------------
__global__ __launch_bounds__(256) void rmsnorm_kernel(const float* __restrict__ x,
                                                      const float* __restrict__ w,
                                                      unsigned short* __restrict__ out)
{
  const long row = blockIdx.x;
  const float* xr = x + row * DIM;
  float vals[16];
  float ss = 0.0f;
#pragma unroll
  for (int t = 0; t < 16; t++) {
    float v = xr[threadIdx.x + t * 256];
    vals[t] = v; ss += v * v;
  }
#pragma unroll
  for (int o = 32; o > 0; o >>= 1) ss += __shfl_down(ss, o, 64);
  __shared__ float red[4];
  const int wv = threadIdx.x >> 6, ln = threadIdx.x & 63;
  if (ln == 0) red[wv] = ss;
  __syncthreads();
  ss = red[0] + red[1] + red[2] + red[3];
  const float scale = 1.0f / sqrtf(ss * (1.0f / (float)DIM) + 1e-6f);
#pragma unroll
  for (int t = 0; t < 16; t++) {
    int c = threadIdx.x + t * 256;
    out[row * DIM + c] = f2b(vals[t] * scale * w[c]);
  }
}

// ---------------------------------------------------------------------------
// RoPE in-place on bf16 (S,H,HD); cos/sin fp32 (S, HD/2)
// ---------------------------------------------------------------------------
__global__ __launch_bounds__(256) void rope_kernel(unsigned short* __restrict__ xq,
                                                   const float* __restrict__ cosb,
                                                   const float* __restrict__ sinb)
{
  const int idx = blockIdx.x * 256 + threadIdx.x;
  if (idx >= S_LEN * NH * 64) return;
  const int i = idx & 63;
  const int h = (idx >> 6) & (NH - 1);
  const int s = idx >> 11;
  const long base = (long)s * DIM + h * HD + 2 * i;
  const float xr = b2f(xq[base]), xi = b2f(xq[base + 1]);
  const float c = cosb[s * 64 + i], sn = sinb[s * 64 + i];
  xq[base]     = f2b(xr * c - xi * sn);
  xq[base + 1] = f2b(xr * sn + xi * c);
}

// ---------------------------------------------------------------------------
// Causal softmax in-place on one bf16 score row; zeros above diagonal
// ---------------------------------------------------------------------------
__global__ __launch_bounds__(256) void softmax_kernel(unsigned short* __restrict__ sc)
{
  const int s  = blockIdx.x;
  const int hz = blockIdx.y;
  unsigned short* row = sc + ((long)hz * S_LEN + s) * S_LEN;
  __shared__ float buf[S_LEN];
  __shared__ float redA[4], redB[4];
  const int tid = threadIdx.x;
  const int wv = tid >> 6, ln = tid & 63;
  const int valid = s + 1;

  float mx = -3.0e38f;
  for (int c = tid; c < valid; c += 256) { float v = b2f(row[c]); buf[c] = v; mx = fmaxf(mx, v); }
#pragma unroll
  for (int o = 32; o > 0; o >>= 1) mx = fmaxf(mx, __shfl_down(mx, o, 64));
  if (ln == 0) redA[wv] = mx;
  __syncthreads();
  mx = fmaxf(fmaxf(redA[0], redA[1]), fmaxf(redA[2], redA[3]));

  float sum = 0.0f;
  for (int c = tid; c < valid; c += 256) { float e = __expf(buf[c] - mx); buf[c] = e; sum += e; }
#pragma unroll
  for (int o = 32; o > 0; o >>= 1) sum += __shfl_down(sum, o, 64);
  if (ln == 0) redB[wv] = sum;
  __syncthreads();
  sum = redB[0] + redB[1] + redB[2] + redB[3];
  const float inv = 1.0f / sum;
  for (int c = tid; c < S_LEN; c += 256)
    row[c] = (c < valid) ? f2b(buf[c] * inv) : (unsigned short)0;
}

// ---------------------------------------------------------------------------
// ffin = silu(a1) * a3  (bf16)
// ---------------------------------------------------------------------------
__global__ __launch_bounds__(256) void silu_mul_kernel(const unsigned short* __restrict__ a1,
                                                       const unsigned short* __restrict__ a3,
                                                       unsigned short* __restrict__ o, long n)
{
  const long i = (long)blockIdx.x * 256 + threadIdx.x;
  if (i >= n) return;
  const float xv = b2f(a1[i]);
  const float g = xv / (1.0f + __expf(-xv));
  o[i] = f2b(g * b2f(a3[i]));
}

// ---------------------------------------------------------------------------
// Transpose + cast fp32 (rows x cols) -> bf16 (cols x rows)
// ---------------------------------------------------------------------------
__global__ __launch_bounds__(256) void transpose_cast_kernel(const float* __restrict__ in,
                                                             unsigned short* __restrict__ out,
                                                             int rows, int cols)
{
  __shared__ unsigned short tile[32][33];
  const int c0 = blockIdx.x * 32, r0 = blockIdx.y * 32;
  const int tx = threadIdx.x & 31, ty = threadIdx.x >> 5;
#pragma unroll
  for (int i = 0; i < 4; i++) {
    int rr = ty + i * 8;
    tile[rr][tx] = f2b(in[(long)(r0 + rr) * cols + (c0 + tx)]);
  }
  __syncthreads();
#pragma unroll
  for (int i = 0; i < 4; i++) {
    int rr = ty + i * 8;
    out[(long)(c0 + rr) * rows + (r0 + tx)] = tile[tx][rr];
  }
}

// ---------------------------------------------------------------------------
// Batched bf16 transpose
// ---------------------------------------------------------------------------
__global__ __launch_bounds__(256) void transpose_bf16_kernel(const unsigned short* __restrict__ in,
                                                             long in_bs, int ld_in,
                                                             unsigned short* __restrict__ out,
                                                             long out_bs, int ld_out,
                                                             int rows, int cols)
{
  const int b = blockIdx.z;
  in  += (long)b * in_bs;
  out += (long)b * out_bs;
  __shared__ unsigned short tile[32][33];
  const int c0 = blockIdx.x * 32, r0 = blockIdx.y * 32;
  const int tx = threadIdx.x & 31, ty = threadIdx.x >> 5;
#pragma unroll
  for (int i = 0; i < 4; i++)
    tile[ty + i * 8][tx] = in[(long)(r0 + ty + i * 8) * ld_in + (c0 + tx)];
  __syncthreads();
#pragma unroll
  for (int i = 0; i < 4; i++)
    out[(long)(c0 + ty + i * 8) * ld_out + (r0 + tx)] = tile[tx][ty + i * 8];
}

// ---------------------------------------------------------------------------
extern "C" void kernel_launch(void* const* d_in, const int* in_sizes, int n_in,
                              void* d_out, int out_size, void* d_ws, size_t ws_size,
                              hipStream_t stream)
{
  const float* x    = (const float*)d_in[0];
  const float* wq   = (const float*)d_in[1];
  const float* wk   = (const float*)d_in[2];
  const float* wv   = (const float*)d_in[3];
  const float* wo   = (const float*)d_in[4];
  const float* w1   = (const float*)d_in[5];
  const float* w2   = (const float*)d_in[6];   // NOTE: w2 before w3 in dict order
  const float* w3   = (const float*)d_in[7];
  const float* anw  = (const float*)d_in[8];
  const float* fnw  = (const float*)d_in[9];
  const float* cosb = (const float*)d_in[10];
  const float* sinb = (const float*)d_in[11];
  float* out = (float*)d_out;

  // workspace layout (~310 MB, phase-overlaid)
  char* ws = (char*)d_ws;
  size_t o = 0;
  unsigned short* wT   = (unsigned short*)(ws + o); o += 90177536ULL;
  unsigned short* hn   = (unsigned short*)(ws + o); o += 16777216ULL;
  unsigned short* attnb= (unsigned short*)(ws + o); o += 16777216ULL;
  float*          hbuf = (float*)(ws + o);          o += 33554432ULL;
  unsigned short* fn   = (unsigned short*)(ws + o); o += 16777216ULL;
  char* ovl = ws + o;
  unsigned short* qb = (unsigned short*)(ovl);
  unsigned short* kb = (unsigned short*)(ovl + 16777216ULL);
  unsigned short* vb = (unsigned short*)(ovl + 2 * 16777216ULL);
  unsigned short* vT = (unsigned short*)(ovl + 3 * 16777216ULL);
  unsigned short* sc = (unsigned short*)(ovl + 4 * 16777216ULL);
  unsigned short* a1   = (unsigned short*)(ovl);
  unsigned short* a3   = (unsigned short*)(ovl + 45088768ULL);
  unsigned short* ffin = (unsigned short*)(ovl + 2 * 45088768ULL);

  const dim3 blk(256);
  const dim3 blk512(512);
  const dim3 tgD(DIM / 32, DIM / 32);
  const dim3 gD256(DIM / QBN, S_LEN / QBM);   // 16 x 8
  const dim3 gFF256(FF / QBN, S_LEN / QBM);   // 43 x 8

  // 1. hn = rmsnorm(x, attn_norm_w)
  rmsnorm_kernel<<<S_LEN, blk, 0, stream>>>(x, anw, hn);

  // 2. q,k,v = hn @ {wq,wk,wv}
  transpose_cast_kernel<<<tgD, blk, 0, stream>>>(wq, wT, DIM, DIM);
  gemm256<<<gD256, blk512, 0, stream>>>(hn, DIM, wT, DIM, qb, DIM, nullptr,
                                        S_LEN, DIM, DIM, 1.0f, 0);
  transpose_cast_kernel<<<tgD, blk, 0, stream>>>(wk, wT, DIM, DIM);
  gemm256<<<gD256, blk512, 0, stream>>>(hn, DIM, wT, DIM, kb, DIM, nullptr,
                                        S_LEN, DIM, DIM, 1.0f, 0);
  transpose_cast_kernel<<<tgD, blk, 0, stream>>>(wv, wT, DIM, DIM);
  gemm256<<<gD256, blk512, 0, stream>>>(hn, DIM, wT, DIM, vb, DIM, nullptr,
                                        S_LEN, DIM, DIM, 1.0f, 0);

  // 3. RoPE on q, k (in place)
  rope_kernel<<<(S_LEN * NH * 64) / 256, blk, 0, stream>>>(qb, cosb, sinb);
  rope_kernel<<<(S_LEN * NH * 64) / 256, blk, 0, stream>>>(kb, cosb, sinb);

  // 4. vT[h][d][s] = v[s][h][d]
  const dim3 tv(HD / 32, S_LEN / 32, NH);
  transpose_bf16_kernel<<<tv, blk, 0, stream>>>(vb, (long)HD, DIM,
                                                vT, (long)HD * S_LEN, S_LEN, S_LEN, HD);

  // 5. attention, 4 chunks of 8 heads (128-tile kernel; PV has N=128)
  const float sscale = 0.08838834764831845f;  // 1/sqrt(128)
  for (int ch = 0; ch < 4; ch++) {
    const int h0 = ch * 8;
    const dim3 gs(S_LEN / BN, S_LEN / BM, 8);
    gemm_bt<<<gs, blk, 0, stream>>>(qb + h0 * HD, DIM, (long)HD,
                                    kb + h0 * HD, DIM, (long)HD,
                                    sc, S_LEN, (long)S_LEN * S_LEN, nullptr,
                                    S_LEN, S_LEN, HD, sscale, GF_CSKIP);
    const dim3 gsm(S_LEN, 8);
    softmax_kernel<<<gsm, blk, 0, stream>>>(sc);
    const dim3 gpv(HD / BN, S_LEN / BM, 8);
    gemm_bt<<<gpv, blk, 0, stream>>>(sc, S_LEN, (long)S_LEN * S_LEN,
                                     vT + (long)h0 * HD * S_LEN, S_LEN, (long)HD * S_LEN,
                                     attnb + h0 * HD, DIM, (long)HD, nullptr,
                                     S_LEN, HD, S_LEN, 1.0f, GF_CKLIM);
  }

  // 6. h = x + attn @ wo
  transpose_cast_kernel<<<tgD, blk, 0, stream>>>(wo, wT, DIM, DIM);
  gemm256<<<gD256, blk512, 0, stream>>>(attnb, DIM, wT, DIM, hbuf, DIM, x,
                                        S_LEN, DIM, DIM, 1.0f, GF_OUTF32 | GF_RES);

  // 7. fn = rmsnorm(h, ffn_norm_w)
  rmsnorm_kernel<<<S_LEN, blk, 0, stream>>>(hbuf, fnw, fn);

  // 8. a1 = fn@w1 ; a3 = fn@w3
  const dim3 tg1(FF / 32, DIM / 32);
  transpose_cast_kernel<<<tg1, blk, 0, stream>>>(w1, wT, DIM, FF);
  gemm256<<<gFF256, blk512, 0, stream>>>(fn, DIM, wT, DIM, a1, FF, nullptr,
                                         S_LEN, FF, DIM, 1.0f, 0);
  transpose_cast_kernel<<<tg1, blk, 0, stream>>>(w3, wT, DIM, FF);
  gemm256<<<gFF256, blk512, 0, stream>>>(fn, DIM, wT, DIM, a3, FF, nullptr,
                                         S_LEN, FF, DIM, 1.0f, 0);

  // 9. ffin = silu(a1) * a3
  silu_mul_kernel<<<(S_LEN * FF) / 256, blk, 0, stream>>>(a1, a3, ffin, (long)S_LEN * FF);

  // 10. out = h + ffin @ w2
  const dim3 tg2(DIM / 32, FF / 32);
  transpose_cast_kernel<<<tg2, blk, 0, stream>>>(w2, wT, FF, DIM);
  gemm256<<<gD256, blk512, 0, stream>>>(ffin, FF, wT, FF, out, DIM, hbuf,
                                        S_LEN, DIM, FF, 1.0f, GF_OUTF32 | GF_RES);
}